// Round 15
// baseline (422.931 us; speedup 1.0000x reference)
//
#include <hip/hip_runtime.h>
#include <hip/hip_fp16.h>

// Weight-stationary LSTM classifier — SELF-REGISTERED XCD groups (round 15).
// Hypothesis: the b&7==XCD assumption was false, so every step ran the slow
// release path (per-step buffer_wbl2) since R8. Fix: 248 wgs (1/CU via 100KB
// LDS; pigeonhole -> every XCD hosts >=24 wgs), each wg reads XCC_ID and
// fetch_adds cnt[xcd]: slot<19 -> main (group=xcd, nb=slot), rest exit.
// Group==XCD by construction -> ALL flag stores relaxed (no wbl2 ever);
// acquire fence only on slot reuse + one entry fence (replay hygiene).
// Geometry = R12 verbatim: 8 groups x 512 rows x 19 wgs (16 jh x 4 gates),
// 1024 thr, W frag-blocked in LDS (conflict-free), exchange slots in MFMA
// frag layout, xpart before wait (x staged 2 ahead), virgin-slot rotation.
// New: h-stores via per-wave LDS f32 transpose -> full 16B-line stores
// (replaces 2B scatter; kills L2 partial-sector RMW).
// d_ws: [0,64KB) flags+cnt, then depth x 5.24MB swizzled slots.

#define TT 22
#define STEPS 22
#define NB 19
#define NWG 248
#define NTHR 1024
#define KTOT 20                  // kt blocks (640 halves: x 0..319 | h 320..639)
#define BUFELT ((size_t)256 * KTOT * 512)
#define SROWS 27                 // staging rows per wg (ceil 512/19)

typedef _Float16 f16;
typedef _Float16 f16x8 __attribute__((ext_vector_type(8)));
typedef float    f32x4 __attribute__((ext_vector_type(4)));

__device__ __forceinline__ float sigm(float x) { return 1.0f / (1.0f + __expf(-x)); }
__device__ __forceinline__ float tanh_f(float x) {
    float ax = fabsf(x);
    float e = __expf(-2.0f * ax);
    return copysignf((1.0f - e) / (1.0f + e), x);
}
__device__ __forceinline__ f16x8 pack8(float4 a, float4 b) {
    f16x8 v;
    v[0] = (f16)a.x; v[1] = (f16)a.y; v[2] = (f16)a.z; v[3] = (f16)a.w;
    v[4] = (f16)b.x; v[5] = (f16)b.y; v[6] = (f16)b.z; v[7] = (f16)b.w;
    return v;
}

__global__ __launch_bounds__(NTHR, 4)
void lstm_ws(const int* __restrict__ cap, const int* __restrict__ cap_len,
             const float* __restrict__ embed,
             const float* __restrict__ Wih, const float* __restrict__ Whh,
             const float* __restrict__ bih, const float* __restrict__ bhh,
             const float* __restrict__ v_wn, const float* __restrict__ g_wn,
             const float* __restrict__ b_cls,
             f16* __restrict__ bufs, int depth,
             unsigned* __restrict__ bar, float* __restrict__ out)
{
    __shared__ f16 Wl[80 * 512];        // 80 KB fragment-blocked W (4g x 20kt)
    __shared__ float ts[16][16][17];    // 17.4 KB h-transpose tiles (per wave)
    __shared__ int capS[SROWS][TT];
    __shared__ float scaleS[2];
    __shared__ int roleS;

    const int tid = threadIdx.x;
    const int wv = tid >> 6, ln = tid & 63, c = ln & 15, kg = ln >> 4;

    // entry hygiene: drop stale L1/L2-clean lines from a previous replay
    __builtin_amdgcn_fence(__ATOMIC_ACQUIRE, "agent");

    // ---- self-registration: role = (physical XCD, slot) ----
    unsigned* cnt = bar + 12288;        // 8 counters, 256B apart
    if (tid == 0) {
        unsigned xcc;
        asm volatile("s_getreg_b32 %0, hwreg(HW_REG_XCC_ID)" : "=s"(xcc));
        unsigned s = __hip_atomic_fetch_add(cnt + xcc * 64, 1u,
                                            __ATOMIC_RELAXED,
                                            __HIP_MEMORY_SCOPE_AGENT);
        roleS = (int)(xcc * 32 + s);
    }
    __syncthreads();
    const int grp = roleS >> 5;
    const int nb  = roleS & 31;
    if (nb >= NB) return;               // surplus wg: exit (group has its 19)

    const int mrow0 = grp * 512;
    unsigned* flags = bar + grp * 1024; // wg flag at + nb*32

    auto slot = [&](int n) { return bufs + (size_t)(n % depth) * BUFELT; };

    // ---- W -> LDS, fragment-blocked (conflict-free b128 reads) ----
    for (int u = tid; u < 80 * 64; u += NTHR) {
        int f = u >> 6, l = u & 63;
        int g = f / KTOT, kt = f - g * KTOT;
        int cc = l & 15, kgg = l >> 4;
        int jh0 = nb * 16 + cc;
        int j = g * 300 + jh0;
        int kb = kt * 32 + kgg * 8;
        f16x8 v;
        #pragma unroll
        for (int i = 0; i < 8; ++i) {
            int kk = kb + i;
            float x = 0.f;
            if (jh0 < 300) {
                if (kk < 300)                   x = Wih[(size_t)j * 300 + kk];
                else if (kk >= 320 && kk < 620) x = Whh[(size_t)j * 300 + (kk - 320)];
            }
            v[i] = (f16)x;
        }
        *(f16x8*)&Wl[(size_t)f * 512 + l * 8] = v;
    }

    const int srow0 = nb * SROWS;
    const int nr = (512 - srow0) < SROWS ? (512 - srow0) : SROWS;  // 27/26
    for (int u = tid; u < SROWS * TT; u += NTHR) {
        int rl = u / TT, t = u - rl * TT;
        if (rl < nr) capS[rl][t] = cap[(size_t)(mrow0 + srow0 + rl) * TT + t];
    }
    if (tid < 2) {
        float s = 0.f;
        for (int k = 0; k < 300; ++k) { float v = v_wn[tid * 300 + k]; s += v * v; }
        scaleS[tid] = g_wn[tid] * rsqrtf(s);
    }
    __syncthreads();

    // ---- x staging into swizzled slot layout ----
    auto stage_x = [&](int t, f16* bufn) {
        for (int u = tid; u < nr * 40; u += NTHR) {
            int rl = u / 40, k8 = u - rl * 40;
            int grow = mrow0 + srow0 + rl;
            const float* er = embed + (size_t)capS[rl][t] * 300;
            int k0 = k8 * 8;
            f16x8 v;
            if (k0 < 296) {
                v = pack8(*(const float4*)(er + k0), *(const float4*)(er + k0 + 4));
            } else if (k0 == 296) {
                float4 a = *(const float4*)(er + 296);
                v[0] = (f16)a.x; v[1] = (f16)a.y; v[2] = (f16)a.z; v[3] = (f16)a.w;
                v[4] = v[5] = v[6] = v[7] = (f16)0.f;
            } else {
                #pragma unroll
                for (int i = 0; i < 8; ++i) v[i] = (f16)0.f;
            }
            size_t off = ((size_t)((grow >> 4) * KTOT + (k8 >> 2))) * 512
                         + (grow & 15) * 32 + (k8 & 3) * 8;
            *(f16x8*)(bufn + off) = v;
        }
    };

    // ---- group barrier: arrive ALWAYS relaxed (same-XCD by construction) ----
    auto arrive = [&](unsigned ph) {
        __syncthreads();   // drains all waves' vmem stores (into shared L2)
        if (tid == 0)
            __hip_atomic_store(flags + nb * 32, ph, __ATOMIC_RELAXED,
                               __HIP_MEMORY_SCOPE_AGENT);
    };
    auto wait = [&](unsigned ph, bool fen) {
        if (tid < NB) {
            while (__hip_atomic_load(flags + tid * 32, __ATOMIC_RELAXED,
                                     __HIP_MEMORY_SCOPE_AGENT) < ph)
                __builtin_amdgcn_s_sleep(1);
        }
        if (fen)   // slot reuse: invalidate stale L1 (dirty L2 preserved)
            __builtin_amdgcn_fence(__ATOMIC_ACQUIRE, "agent");
        __syncthreads();
    };

    // per-lane constants
    size_t aoff[2];
    #pragma unroll
    for (int m = 0; m < 2; ++m)
        aoff[m] = (size_t)(((mrow0 >> 4) + wv * 2 + m) * KTOT) * 512
                  + c * 32 + kg * 8;
    int wbase[4];
    #pragma unroll
    for (int g = 0; g < 4; ++g) wbase[g] = g * KTOT * 512 + ln * 8;

    const int jh = nb * 16 + c;
    float bias[4];
    #pragma unroll
    for (int g = 0; g < 4; ++g) {
        float bv = 0.f;
        if (jh < 300) { int j = g * 300 + jh; bv = bih[j] + bhh[j]; }
        bias[g] = bv;
    }
    int lenr[2][4];
    #pragma unroll
    for (int m = 0; m < 2; ++m) {
        int rb = mrow0 + wv * 32 + m * 16 + kg * 4;
        #pragma unroll
        for (int rg = 0; rg < 4; ++rg) lenr[m][rg] = cap_len[rb + rg];
    }
    // h stripe constants: cols [nb*16, nb*16+16) land contiguously in-block
    const int hkt   = 10 + (nb >> 1);        // (320 + nb*16) >> 5
    const int kbase = (nb & 1) * 16;         // (320 + nb*16) & 31

    float cst[2][4] = {};
    float hreg[2][4] = {};
    f32x4 acc[2][4];

    auto xpart = [&](const f16* bufc) {
        #pragma unroll
        for (int kt = 0; kt < 10; ++kt) {
            f16x8 av[2];
            #pragma unroll
            for (int m = 0; m < 2; ++m)
                av[m] = *(const f16x8*)(bufc + aoff[m] + kt * 512);
            #pragma unroll
            for (int g = 0; g < 4; ++g) {
                f16x8 bv = *(const f16x8*)&Wl[wbase[g] + kt * 512];
                #pragma unroll
                for (int m = 0; m < 2; ++m)
                    acc[m][g] = __builtin_amdgcn_mfma_f32_16x16x32_f16(av[m], bv, acc[m][g], 0, 0, 0);
            }
        }
    };
    auto hpart = [&](const f16* bufc) {
        #pragma unroll
        for (int kt = 10; kt < KTOT; ++kt) {
            f16x8 av[2];
            #pragma unroll
            for (int m = 0; m < 2; ++m)
                av[m] = *(const f16x8*)(bufc + aoff[m] + kt * 512);
            #pragma unroll
            for (int g = 0; g < 4; ++g) {
                f16x8 bv = *(const f16x8*)&Wl[wbase[g] + kt * 512];
                #pragma unroll
                for (int m = 0; m < 2; ++m)
                    acc[m][g] = __builtin_amdgcn_mfma_f32_16x16x32_f16(av[m], bv, acc[m][g], 0, 0, 0);
            }
        }
    };

    const bool ahead2 = (depth >= 3);
    stage_x(0, slot(0));                 // slot0 fully memset (h_0=0 + pads)
    if (ahead2) stage_x(1, slot(1));
    arrive(1);
    wait(1, false);

    #pragma unroll 1
    for (int t = 0; t < STEPS; ++t) {
        const f16* bufc = slot(t);
        #pragma unroll
        for (int m = 0; m < 2; ++m)
            #pragma unroll
            for (int g = 0; g < 4; ++g) {
                float bv = bias[g];
                f32x4 b4 = {bv, bv, bv, bv};
                acc[m][g] = b4;
            }

        bool reuse = (unsigned)(t + 1) >= (unsigned)depth;
        if (ahead2) {
            xpart(bufc);                  // x(t) covered by wait(t) last iter
            wait((unsigned)(t + 1), reuse);
        } else {
            wait((unsigned)(t + 1), reuse);
            xpart(bufc);
        }
        hpart(bufc);

        // gates (i/f/g/o same-lane acc regs); h via LDS transpose -> 16B stores
        f16* bufn = slot(t + 1);
        #pragma unroll
        for (int m = 0; m < 2; ++m) {
            #pragma unroll
            for (int rg = 0; rg < 4; ++rg) {
                bool upd = (t < lenr[m][rg]);
                float iv = sigm(acc[m][0][rg]);
                float fv = sigm(acc[m][1][rg]);
                float gv = tanh_f(acc[m][2][rg]);
                float ov = sigm(acc[m][3][rg]);
                float cn = fv * cst[m][rg] + iv * gv;
                cn = upd ? cn : cst[m][rg];
                cst[m][rg] = cn;
                float hn = ov * tanh_f(cn);
                hreg[m][rg] = upd ? hn : hreg[m][rg];
                ts[wv][kg * 4 + rg][c] = (jh < 300) ? hreg[m][rg] : 0.f;
            }
            // wave-local transposed readback: 32 lanes x one f16x8 line store
            if (ln < 32) {
                int r = ln >> 1, hf = ln & 1;
                f16x8 v;
                #pragma unroll
                for (int i = 0; i < 8; ++i) v[i] = (f16)ts[wv][r][hf * 8 + i];
                int rtile = (mrow0 >> 4) + wv * 2 + m;
                size_t dst = ((size_t)(rtile * KTOT + hkt)) * 512
                             + r * 32 + kbase + hf * 8;
                *(f16x8*)(bufn + dst) = v;
            }
        }

        if (ahead2) { if (t + 2 < STEPS) stage_x(t + 2, slot(t + 2)); }
        else        { if (t + 1 < STEPS) stage_x(t + 1, slot(t + 1)); }
        arrive((unsigned)(t + 2));
    }

    wait((unsigned)(STEPS + 1), true);

    // ---- head: this wg's staged rows, swizzled h reads ----
    const f16* hb = slot(STEPS);
    for (int u = tid; u < nr * 2; u += NTHR) {
        int rl = u >> 1, cls = u & 1;
        int grow = mrow0 + srow0 + rl;
        float sc = scaleS[cls];
        const float* vr = v_wn + cls * 300;
        size_t rbase = ((size_t)((grow >> 4) * KTOT)) * 512 + (grow & 15) * 32;
        float s = 0.f;
        #pragma unroll 4
        for (int k = 0; k < 300; ++k) {
            int k2 = 320 + k;
            size_t off = rbase + (size_t)(k2 >> 5) * 512 + (k2 & 31);
            s += vr[k] * (float)hb[off];
        }
        out[(size_t)grow * 2 + cls] = sc * s + b_cls[cls];
    }
}

extern "C" void kernel_launch(void* const* d_in, const int* in_sizes, int n_in,
                              void* d_out, int out_size, void* d_ws, size_t ws_size,
                              hipStream_t stream) {
    const int*   cap     = (const int*)  d_in[0];
    const int*   cap_len = (const int*)  d_in[1];
    const float* embed   = (const float*)d_in[2];
    const float* W_ih    = (const float*)d_in[3];
    const float* W_hh    = (const float*)d_in[4];
    const float* b_ih    = (const float*)d_in[5];
    const float* b_hh    = (const float*)d_in[6];
    const float* v_wn    = (const float*)d_in[7];
    const float* g_wn    = (const float*)d_in[8];
    const float* b_cls   = (const float*)d_in[9];
    float* out = (float*)d_out;

    unsigned* bar = (unsigned*)d_ws;
    f16* bufs = (f16*)((char*)d_ws + 65536);
    size_t slot_bytes = BUFELT * sizeof(f16);          // 5,242,880
    int depth = (int)((ws_size > 65536 ? ws_size - 65536 : 0) / slot_bytes);
    if (depth > STEPS + 1) depth = STEPS + 1;          // 23 = fully virgin
    if (depth < 2) depth = 2;

    hipMemsetAsync(bar, 0, 65536, stream);             // flags + reg counters
    hipMemsetAsync(bufs, 0, slot_bytes, stream);       // slot 0 (h_0=0 + pads)

    lstm_ws<<<NWG, NTHR, 0, stream>>>(cap, cap_len, embed, W_ih, W_hh, b_ih, b_hh,
                                      v_wn, g_wn, b_cls, bufs, depth, bar, out);
}